// Round 1
// baseline (3021.681 us; speedup 1.0000x reference)
//
#include <hip/hip_runtime.h>
#include <hip/hip_bf16.h>
#include <stdint.h>
#include <math.h>

#define NBATCH 4
#define NANCH 36864
#define PRE 6000
#define POST 300

// ---------------- workspace layout (float units) ----------------
static constexpr size_t WT_OFF  = 0;                         // transposed conv_w [ci][tap][co]
static constexpr size_t WT_SZ   = 512ull * 512 * 9;
static constexpr size_t H_OFF   = WT_OFF + WT_SZ;            // conv output [b][c][y][x]
static constexpr size_t H_SZ    = 4ull * 512 * 64 * 64;
static constexpr size_t BOX_OFF = H_OFF + H_SZ;              // clipped boxes [b][i][4]
static constexpr size_t BOX_SZ  = 4ull * NANCH * 4;
static constexpr size_t KEY_OFF = BOX_OFF + BOX_SZ;          // sortable keys [b][i] (uint)
static constexpr size_t KEY_SZ  = 4ull * NANCH;
static constexpr size_t SEL_OFF = KEY_OFF + KEY_SZ;          // per batch: x1,y1,x2,y2,score SoA [5][PRE]

// ---------------- d_out layout (float units) ----------------
static constexpr size_t OFF_OFFSETS = 0;                     // [4][36864][4]
static constexpr size_t OFF_CLS     = 589824;                // [4][36864][2]
static constexpr size_t OFF_ROIS    = 884736;                // [4][300][4]
static constexpr size_t OFF_RIDX    = 889536;                // [4][300]
static constexpr size_t OFF_ANCH    = 890736;                // [36864][4]

// anchor base computed in double precision (matches numpy) then rounded to f32
__constant__ float c_ab[9][4] = {
  {-37.254833995939044f,  -82.509667991878088f,  52.254833995939044f,  97.509667991878088f},
  {-82.509667991878088f, -173.019335983756176f,  97.509667991878088f, 188.019335983756176f},
  {-173.019335983756176f,-354.038671967512352f, 188.019335983756176f, 369.038671967512352f},
  {-56.f, -56.f, 71.f, 71.f},
  {-120.f,-120.f,135.f,135.f},
  {-248.f,-248.f,263.f,263.f},
  {-82.509667991878088f,  -37.254833995939044f,  97.509667991878088f,  52.254833995939044f},
  {-173.019335983756176f, -82.509667991878088f, 188.019335983756176f,  97.509667991878088f},
  {-354.038671967512352f,-173.019335983756176f, 369.038671967512352f, 188.019335983756176f},
};

// ---------------- kernel 0: transpose conv weights to [ci][tap][co] ----------------
__global__ void k_transpose_w(const float* __restrict__ w, float* __restrict__ wT) {
  const int i = blockIdx.x * 256 + threadIdx.x;
  if (i >= 512 * 512 * 9) return;
  const int ci  = i / (9 * 512);
  const int r   = i - ci * (9 * 512);
  const int tap = r >> 9;
  const int co  = r & 511;
  wT[i] = w[((size_t)co * 512 + ci) * 9 + tap];
}

// ---------------- kernel 1: conv3x3 + bias + relu ----------------
// grid (16 row-tiles, 8 co-chunks, 4 batches), block 256
// block tile: 64 co x 4 rows x 64 cols; per-thread 4co x 4row x 4col
__global__ __launch_bounds__(256, 2)
void k_conv3(const float* __restrict__ x, const float* __restrict__ wT,
             const float* __restrict__ bias, float* __restrict__ h) {
  __shared__ float in_lds[8 * 6 * 66];   // [ck][ir 0..5][c 0..65], c has zero cols at 0,65
  __shared__ float w_lds[8 * 9 * 64];    // [ck][tap][co]
  const int t   = threadIdx.x;
  const int b   = blockIdx.z;
  const int co0 = blockIdx.y * 64;
  const int y0  = blockIdx.x * 4;
  const int tx  = t & 15;   // cols tx*4 .. +3
  const int ty  = t >> 4;   // co  co0+ty*4 .. +3

  float acc[4][4][4];  // [row][col][co]
  #pragma unroll
  for (int a = 0; a < 4; ++a)
    #pragma unroll
    for (int c = 0; c < 4; ++c)
      #pragma unroll
      for (int j = 0; j < 4; ++j) acc[a][c][j] = 0.f;

  for (int c0 = 0; c0 < 512; c0 += 8) {
    __syncthreads();
    for (int i = t; i < 8 * 6 * 66; i += 256) {
      const int ck = i / 396;
      const int rr = i - ck * 396;
      const int ir = rr / 66;
      const int cc = rr - ir * 66;
      const int gy = y0 - 1 + ir;
      float v = 0.f;
      if (cc >= 1 && cc <= 64 && gy >= 0 && gy < 64)
        v = x[(size_t)(((b * 512) + c0 + ck) * 64 + gy) * 64 + (cc - 1)];
      in_lds[i] = v;
    }
    for (int i = t; i < 8 * 9 * 64; i += 256) {
      const int ck = i / 576;
      const int rr = i - ck * 576;
      w_lds[i] = wT[(size_t)((c0 + ck) * 9 + (rr >> 6)) * 512 + co0 + (rr & 63)];
    }
    __syncthreads();
    for (int ck = 0; ck < 8; ++ck) {
      float wv[9][4];
      #pragma unroll
      for (int tap = 0; tap < 9; ++tap)
        *(float4*)&wv[tap][0] = *(const float4*)&w_lds[ck * 576 + tap * 64 + ty * 4];
      #pragma unroll
      for (int ir = 0; ir < 6; ++ir) {
        float iv[6];
        #pragma unroll
        for (int k = 0; k < 6; ++k)
          iv[k] = in_lds[ck * 396 + ir * 66 + tx * 4 + k];
        #pragma unroll
        for (int dy = 0; dy < 3; ++dy) {
          const int lr = ir - dy;
          if (lr < 0 || lr > 3) continue;
          #pragma unroll
          for (int dx = 0; dx < 3; ++dx) {
            #pragma unroll
            for (int cc = 0; cc < 4; ++cc) {
              const float ivv = iv[cc + dx];
              #pragma unroll
              for (int j = 0; j < 4; ++j)
                acc[lr][cc][j] = fmaf(wv[dy * 3 + dx][j], ivv, acc[lr][cc][j]);
            }
          }
        }
      }
    }
  }
  #pragma unroll
  for (int j = 0; j < 4; ++j) {
    const int co = co0 + ty * 4 + j;
    const float bv = bias[co];
    #pragma unroll
    for (int lr = 0; lr < 4; ++lr) {
      float4 o;
      o.x = fmaxf(acc[lr][0][j] + bv, 0.f);
      o.y = fmaxf(acc[lr][1][j] + bv, 0.f);
      o.z = fmaxf(acc[lr][2][j] + bv, 0.f);
      o.w = fmaxf(acc[lr][3][j] + bv, 0.f);
      *(float4*)&h[(size_t)(((b * 512 + co) * 64) + y0 + lr) * 64 + tx * 4] = o;
    }
  }
}

// ---------------- kernel 2: 1x1 heads + softmax + decode + keys ----------------
// grid (64 rows, 4 batches), block 256; thread = (px = t&63, og = t>>6), och = og*14+j
__global__ __launch_bounds__(256, 1)
void k_heads(const float* __restrict__ h, const float* __restrict__ cls_w,
             const float* __restrict__ cls_b, const float* __restrict__ reg_w,
             const float* __restrict__ reg_b, const int* __restrict__ im_h_p,
             const int* __restrict__ im_w_p, float* __restrict__ out,
             float* __restrict__ ws) {
  __shared__ float w_lds[56 * 512];
  __shared__ float h_lds[64 * 64];
  __shared__ float o_lds[56 * 64];
  const int t = threadIdx.x;
  const int y = blockIdx.x;
  const int b = blockIdx.y;
  for (int i = t; i < 56 * 512; i += 256) {
    const int och = i >> 9, ci = i & 511;
    float v = 0.f;
    if (och < 18) v = cls_w[och * 512 + ci];
    else if (och < 54) v = reg_w[(och - 18) * 512 + ci];
    w_lds[i] = v;
  }
  const int px = t & 63, og = t >> 6;
  float acc[14];
  #pragma unroll
  for (int j = 0; j < 14; ++j) acc[j] = 0.f;
  for (int c0 = 0; c0 < 512; c0 += 64) {
    __syncthreads();
    for (int i = t; i < 4096; i += 256)
      h_lds[i] = h[(size_t)((b * 512 + c0 + (i >> 6)) * 64 + y) * 64 + (i & 63)];
    __syncthreads();
    #pragma unroll 4
    for (int ci = 0; ci < 64; ci += 4) {
      const float hv0 = h_lds[(ci + 0) * 64 + px];
      const float hv1 = h_lds[(ci + 1) * 64 + px];
      const float hv2 = h_lds[(ci + 2) * 64 + px];
      const float hv3 = h_lds[(ci + 3) * 64 + px];
      #pragma unroll
      for (int j = 0; j < 14; ++j) {
        const float4 wv = *(const float4*)&w_lds[(og * 14 + j) * 512 + c0 + ci];
        acc[j] = fmaf(hv0, wv.x, fmaf(hv1, wv.y, fmaf(hv2, wv.z, fmaf(hv3, wv.w, acc[j]))));
      }
    }
  }
  __syncthreads();
  #pragma unroll
  for (int j = 0; j < 14; ++j) {
    const int och = og * 14 + j;
    float bv = 0.f;
    if (och < 18) bv = cls_b[och];
    else if (och < 54) bv = reg_b[och - 18];
    o_lds[och * 64 + px] = acc[j] + bv;
  }
  __syncthreads();
  const float imw1 = (float)(*im_w_p) - 1.0f;
  const float imh1 = (float)(*im_h_p) - 1.0f;
  for (int ii = t; ii < 576; ii += 256) {
    const int p = ii / 9, a = ii - (ii / 9) * 9;
    const int gi = (y * 64 + p) * 9 + a;
    const float l0 = o_lds[(a * 2) * 64 + p];
    const float l1 = o_lds[(a * 2 + 1) * 64 + p];
    out[OFF_CLS + (size_t)b * 73728 + (size_t)gi * 2 + 0] = l0;
    out[OFF_CLS + (size_t)b * 73728 + (size_t)gi * 2 + 1] = l1;
    const float m  = fmaxf(l0, l1);
    const float e0 = expf(l0 - m), e1 = expf(l1 - m);
    const float score = e1 / (e0 + e1);
    float ofs[4];
    #pragma unroll
    for (int d = 0; d < 4; ++d) {
      ofs[d] = o_lds[(18 + a * 4 + d) * 64 + p];
      out[OFF_OFFSETS + (size_t)b * 147456 + (size_t)gi * 4 + d] = ofs[d];
    }
    const float sx = (float)(p * 16), sy = (float)(y * 16);
    const float a0 = c_ab[a][0] + sx, a1 = c_ab[a][1] + sy;
    const float a2 = c_ab[a][2] + sx, a3 = c_ab[a][3] + sy;
    if (b == 0) {
      out[OFF_ANCH + (size_t)gi * 4 + 0] = a0;
      out[OFF_ANCH + (size_t)gi * 4 + 1] = a1;
      out[OFF_ANCH + (size_t)gi * 4 + 2] = a2;
      out[OFF_ANCH + (size_t)gi * 4 + 3] = a3;
    }
    const float aw  = fmaxf(a2 - a0 + 1.0f, 1e-5f);
    const float ah  = fmaxf(a3 - a1 + 1.0f, 1e-5f);
    const float acx = 0.5f * (a0 + a2), acy = 0.5f * (a1 + a3);
    const float tw  = aw * expf(ofs[2]);
    const float th  = ah * expf(ofs[3]);
    const float tcx = acx + ofs[0] * aw;
    const float tcy = acy + ofs[1] * ah;
    float x1 = tcx - 0.5f * (tw - 1.0f);
    float y1 = tcy - 0.5f * (th - 1.0f);
    float x2 = tcx + 0.5f * (tw - 1.0f);
    float y2 = tcy + 0.5f * (th - 1.0f);
    x1 = fminf(fmaxf(x1, 0.f), imw1);
    x2 = fminf(fmaxf(x2, 0.f), imw1);
    y1 = fminf(fmaxf(y1, 0.f), imh1);
    y2 = fminf(fmaxf(y2, 0.f), imh1);
    const bool valid = ((x2 - x1 + 1.0f) >= 16.0f) && ((y2 - y1 + 1.0f) >= 16.0f);
    const unsigned int key = valid ? __float_as_uint(score) : 0u;
    float* bp = ws + BOX_OFF + ((size_t)b * NANCH + gi) * 4;
    bp[0] = x1; bp[1] = y1; bp[2] = x2; bp[3] = y2;
    ((unsigned int*)(ws + KEY_OFF))[(size_t)b * NANCH + gi] = key;
  }
}

// ---------------- kernel 3: exact top-PRE selection (radix threshold + ordered compaction) ----------------
// grid 4 (one block/batch), block 256
__global__ __launch_bounds__(256, 1)
void k_select(float* __restrict__ ws) {
  const int b = blockIdx.x;
  const int t = threadIdx.x;
  const unsigned int* keys = (const unsigned int*)(ws + KEY_OFF) + (size_t)b * NANCH;
  const float* boxes = ws + BOX_OFF + (size_t)b * NANCH * 4;
  float* sel = ws + SEL_OFF + (size_t)b * 5 * PRE;
  __shared__ unsigned int hist[256];
  __shared__ unsigned int s_prefix, s_need, s_gt_base, s_eq_base;
  __shared__ unsigned int wc_gt[4], wc_eq[4];
  if (t == 0) { s_prefix = 0u; s_need = PRE; s_gt_base = 0u; s_eq_base = 0u; }
  for (int pass = 0; pass < 4; ++pass) {
    hist[t] = 0u;
    __syncthreads();
    const unsigned int prefix = s_prefix;
    const int shift = 24 - 8 * pass;
    for (int i = t; i < NANCH; i += 256) {
      const unsigned int k = keys[i];
      bool match = true;
      if (pass > 0) match = ((k >> (shift + 8)) == (prefix >> (shift + 8)));
      if (match) atomicAdd(&hist[(k >> shift) & 255u], 1u);
    }
    __syncthreads();
    if (t == 0) {
      unsigned int need = s_need, cum = 0u;
      for (int bin = 255; bin >= 0; --bin) {
        const unsigned int hc = hist[bin];
        if (cum + hc >= need) {
          s_prefix = prefix | ((unsigned int)bin << shift);
          s_need = need - cum;
          break;
        }
        cum += hc;
      }
    }
    __syncthreads();
  }
  const unsigned int T = s_prefix;
  const unsigned int need_eq = s_need;          // # of ==T items to take (>=1)
  const unsigned int count_gt = PRE - need_eq;  // # of >T items (exact)
  const int lane = t & 63, wid = t >> 6;
  const unsigned long long lmask = (1ull << lane) - 1ull;
  for (int i0 = 0; i0 < NANCH; i0 += 256) {     // 144 exact chunks, index-ordered
    const int i = i0 + t;
    const unsigned int k = keys[i];
    const bool gt = (k > T);
    const bool eq = (k == T);
    const unsigned long long mg = __ballot(gt);
    const unsigned long long me = __ballot(eq);
    if (lane == 0) { wc_gt[wid] = (unsigned int)__popcll(mg); wc_eq[wid] = (unsigned int)__popcll(me); }
    __syncthreads();
    unsigned int goff = s_gt_base, eoff = s_eq_base, tg = 0u, te = 0u;
    #pragma unroll
    for (int w = 0; w < 4; ++w) {
      if (w < wid) { goff += wc_gt[w]; eoff += wc_eq[w]; }
      tg += wc_gt[w]; te += wc_eq[w];
    }
    int slot = -1;
    if (gt) {
      slot = (int)(goff + (unsigned int)__popcll(mg & lmask));
    } else if (eq) {
      const unsigned int er = eoff + (unsigned int)__popcll(me & lmask);
      if (er < need_eq) slot = (int)(count_gt + er);
    }
    if (slot >= 0) {
      const float* bp = boxes + (size_t)i * 4;
      sel[slot]           = bp[0];
      sel[PRE + slot]     = bp[1];
      sel[2 * PRE + slot] = bp[2];
      sel[3 * PRE + slot] = bp[3];
      sel[4 * PRE + slot] = (k != 0u) ? __uint_as_float(k) : -1.0f;  // -1 == reference's -inf
    }
    __syncthreads();
    if (t == 0) { s_gt_base += tg; s_eq_base += te; }
  }
}

// ---------------- kernel 4: NMS (300 serial steps) + rois_idx ----------------
// grid 4 (one block/batch), block 256
__global__ __launch_bounds__(256, 1)
void k_nms(const float* __restrict__ ws, float* __restrict__ out) {
  const int b = blockIdx.x;
  const int t = threadIdx.x;
  const float* sel = ws + SEL_OFF + (size_t)b * 5 * PRE;
  __shared__ float lx1[PRE], ly1[PRE], lx2[PRE], ly2[PRE], lar[PRE];
  __shared__ float r_s[4];
  __shared__ int   r_p[4];
  float sreg[24];
  #pragma unroll
  for (int j = 0; j < 24; ++j) {
    const int p = j * 256 + t;
    if (p < PRE) {
      const float x1 = sel[p],           y1 = sel[PRE + p];
      const float x2 = sel[2 * PRE + p], y2 = sel[3 * PRE + p];
      lx1[p] = x1; ly1[p] = y1; lx2[p] = x2; ly2[p] = y2;
      lar[p] = (x2 - x1) * (y2 - y1);
      sreg[j] = sel[4 * PRE + p];
    } else {
      sreg[j] = -2.0f;  // pad slot: always loses to real/-1 items
    }
  }
  __syncthreads();
  float fx1 = 0.f, fy1 = 0.f, fx2 = 0.f, fy2 = 0.f;
  const int lane = t & 63, wid = t >> 6;
  for (int it = 0; it < POST; ++it) {
    float bs = -3.0f; int bpos = 0;
    #pragma unroll
    for (int j = 0; j < 24; ++j) {
      const int p = j * 256 + t;
      const float s = sreg[j];
      if (s > bs || (s == bs && p < bpos)) { bs = s; bpos = p; }
    }
    #pragma unroll
    for (int off = 1; off < 64; off <<= 1) {
      const float os = __shfl_xor(bs, off);
      const int   op = __shfl_xor(bpos, off);
      if (os > bs || (os == bs && op < bpos)) { bs = os; bpos = op; }
    }
    if (lane == 0) { r_s[wid] = bs; r_p[wid] = bpos; }
    __syncthreads();
    bs = r_s[0]; bpos = r_p[0];
    #pragma unroll
    for (int w = 1; w < 4; ++w) {
      const float os = r_s[w]; const int op = r_p[w];
      if (os > bs || (os == bs && op < bpos)) { bs = os; bpos = op; }
    }
    __syncthreads();
    const float bx1 = lx1[bpos], by1 = ly1[bpos];
    const float bx2 = lx2[bpos], by2 = ly2[bpos], ba = lar[bpos];
    const bool ok = (bs >= 0.0f);
    if (it == 0) { fx1 = bx1; fy1 = by1; fx2 = bx2; fy2 = by2; }
    if (t == 0) {
      const size_t o = OFF_ROIS + ((size_t)b * POST + it) * 4;
      out[o + 0] = ok ? bx1 : fx1;
      out[o + 1] = ok ? by1 : fy1;
      out[o + 2] = ok ? bx2 : fx2;
      out[o + 3] = ok ? by2 : fy2;
    }
    #pragma unroll
    for (int j = 0; j < 24; ++j) {
      const int p = j * 256 + t;
      if (sreg[j] >= 0.0f) {
        const float xx1 = fmaxf(bx1, lx1[p]);
        const float yy1 = fmaxf(by1, ly1[p]);
        const float xx2 = fminf(bx2, lx2[p]);
        const float yy2 = fminf(by2, ly2[p]);
        const float inter = fmaxf(xx2 - xx1, 0.f) * fmaxf(yy2 - yy1, 0.f);
        const float iou = inter / (ba + lar[p] - inter + 1e-12f);
        if (iou > 0.7f || p == bpos) sreg[j] = -1.0f;
      }
    }
  }
  for (int i = t; i < POST; i += 256)
    out[OFF_RIDX + (size_t)b * POST + i] = (float)b;
}

extern "C" void kernel_launch(void* const* d_in, const int* in_sizes, int n_in,
                              void* d_out, int out_size, void* d_ws, size_t ws_size,
                              hipStream_t stream) {
  const float* x      = (const float*)d_in[0];
  const float* conv_w = (const float*)d_in[1];
  const float* conv_b = (const float*)d_in[2];
  const float* cls_w  = (const float*)d_in[3];
  const float* cls_b  = (const float*)d_in[4];
  const float* reg_w  = (const float*)d_in[5];
  const float* reg_b  = (const float*)d_in[6];
  const int*   im_h   = (const int*)d_in[7];
  const int*   im_w   = (const int*)d_in[8];
  float* out = (float*)d_out;
  float* ws  = (float*)d_ws;

  k_transpose_w<<<(512 * 512 * 9 + 255) / 256, 256, 0, stream>>>(conv_w, ws + WT_OFF);
  k_conv3<<<dim3(16, 8, 4), 256, 0, stream>>>(x, ws + WT_OFF, conv_b, ws + H_OFF);
  k_heads<<<dim3(64, 4), 256, 0, stream>>>(ws + H_OFF, cls_w, cls_b, reg_w, reg_b,
                                           im_h, im_w, out, ws);
  k_select<<<4, 256, 0, stream>>>(ws);
  k_nms<<<4, 256, 0, stream>>>(ws, out);
}

// Round 3
// 1766.031 us; speedup vs baseline: 1.7110x; 1.7110x over previous
//
#include <hip/hip_runtime.h>
#include <hip/hip_bf16.h>
#include <stdint.h>
#include <math.h>

#define NBATCH 4
#define NANCH 36864
#define PRE 6000
#define POST 300

// ---------------- workspace layout (float units) ----------------
static constexpr size_t WT_OFF  = 0;                         // transposed conv_w [ci][tap][co]
static constexpr size_t WT_SZ   = 512ull * 512 * 9;
static constexpr size_t H_OFF   = WT_OFF + WT_SZ;            // conv output [b][c][y][x]; REUSED as NMS mask after k_heads
static constexpr size_t H_SZ    = 4ull * 512 * 64 * 64;
static constexpr size_t BOX_OFF = H_OFF + H_SZ;              // clipped boxes [b][i][4]
static constexpr size_t BOX_SZ  = 4ull * NANCH * 4;
static constexpr size_t KEY_OFF = BOX_OFF + BOX_SZ;          // sortable keys [b][i] (uint)
static constexpr size_t KEY_SZ  = 4ull * NANCH;
static constexpr size_t SEL_OFF = KEY_OFF + KEY_SZ;          // per batch: x1,y1,x2,y2,score SoA [5][PRE]
static constexpr size_t SEL_SZ  = 4ull * 5 * PRE;
static constexpr size_t SKEY_OFF = SEL_OFF + SEL_SZ;         // sorted keys [b][PRE] (uint)
static constexpr size_t SKEY_SZ  = 4ull * PRE;
static constexpr size_t SBOX_OFF = SKEY_OFF + SKEY_SZ;       // sorted boxes SoA [b][4][PRE]
// NMS suppression bitmask: u64[4][PRE][94] = 18 MB, aliased onto H region (dead after k_heads)

// ---------------- d_out layout (float units) ----------------
static constexpr size_t OFF_OFFSETS = 0;                     // [4][36864][4]
static constexpr size_t OFF_CLS     = 589824;                // [4][36864][2]
static constexpr size_t OFF_ROIS    = 884736;                // [4][300][4]
static constexpr size_t OFF_RIDX    = 889536;                // [4][300]
static constexpr size_t OFF_ANCH    = 890736;                // [36864][4]

// anchor base computed in double precision (matches numpy) then rounded to f32
__constant__ float c_ab[9][4] = {
  {-37.254833995939044f,  -82.509667991878088f,  52.254833995939044f,  97.509667991878088f},
  {-82.509667991878088f, -173.019335983756176f,  97.509667991878088f, 188.019335983756176f},
  {-173.019335983756176f,-354.038671967512352f, 188.019335983756176f, 369.038671967512352f},
  {-56.f, -56.f, 71.f, 71.f},
  {-120.f,-120.f,135.f,135.f},
  {-248.f,-248.f,263.f,263.f},
  {-82.509667991878088f,  -37.254833995939044f,  97.509667991878088f,  52.254833995939044f},
  {-173.019335983756176f, -82.509667991878088f, 188.019335983756176f,  97.509667991878088f},
  {-354.038671967512352f,-173.019335983756176f, 369.038671967512352f, 188.019335983756176f},
};

// ---------------- kernel 0: transpose conv weights to [ci][tap][co] ----------------
__global__ void k_transpose_w(const float* __restrict__ w, float* __restrict__ wT) {
  const int i = blockIdx.x * 256 + threadIdx.x;
  if (i >= 512 * 512 * 9) return;
  const int ci  = i / (9 * 512);
  const int r   = i - ci * (9 * 512);
  const int tap = r >> 9;
  const int co  = r & 511;
  wT[i] = w[((size_t)co * 512 + ci) * 9 + tap];
}

// ---------------- kernel 1: conv3x3 + bias + relu ----------------
__global__ __launch_bounds__(256, 2)
void k_conv3(const float* __restrict__ x, const float* __restrict__ wT,
             const float* __restrict__ bias, float* __restrict__ h) {
  __shared__ float in_lds[8 * 6 * 66];
  __shared__ float w_lds[8 * 9 * 64];
  const int t   = threadIdx.x;
  const int b   = blockIdx.z;
  const int co0 = blockIdx.y * 64;
  const int y0  = blockIdx.x * 4;
  const int tx  = t & 15;
  const int ty  = t >> 4;

  float acc[4][4][4];
  #pragma unroll
  for (int a = 0; a < 4; ++a)
    #pragma unroll
    for (int c = 0; c < 4; ++c)
      #pragma unroll
      for (int j = 0; j < 4; ++j) acc[a][c][j] = 0.f;

  for (int c0 = 0; c0 < 512; c0 += 8) {
    __syncthreads();
    for (int i = t; i < 8 * 6 * 66; i += 256) {
      const int ck = i / 396;
      const int rr = i - ck * 396;
      const int ir = rr / 66;
      const int cc = rr - ir * 66;
      const int gy = y0 - 1 + ir;
      float v = 0.f;
      if (cc >= 1 && cc <= 64 && gy >= 0 && gy < 64)
        v = x[(size_t)(((b * 512) + c0 + ck) * 64 + gy) * 64 + (cc - 1)];
      in_lds[i] = v;
    }
    for (int i = t; i < 8 * 9 * 64; i += 256) {
      const int ck = i / 576;
      const int rr = i - ck * 576;
      w_lds[i] = wT[(size_t)((c0 + ck) * 9 + (rr >> 6)) * 512 + co0 + (rr & 63)];
    }
    __syncthreads();
    for (int ck = 0; ck < 8; ++ck) {
      float wv[9][4];
      #pragma unroll
      for (int tap = 0; tap < 9; ++tap)
        *(float4*)&wv[tap][0] = *(const float4*)&w_lds[ck * 576 + tap * 64 + ty * 4];
      #pragma unroll
      for (int ir = 0; ir < 6; ++ir) {
        float iv[6];
        #pragma unroll
        for (int k = 0; k < 6; ++k)
          iv[k] = in_lds[ck * 396 + ir * 66 + tx * 4 + k];
        #pragma unroll
        for (int dy = 0; dy < 3; ++dy) {
          const int lr = ir - dy;
          if (lr < 0 || lr > 3) continue;
          #pragma unroll
          for (int dx = 0; dx < 3; ++dx) {
            #pragma unroll
            for (int cc = 0; cc < 4; ++cc) {
              const float ivv = iv[cc + dx];
              #pragma unroll
              for (int j = 0; j < 4; ++j)
                acc[lr][cc][j] = fmaf(wv[dy * 3 + dx][j], ivv, acc[lr][cc][j]);
            }
          }
        }
      }
    }
  }
  #pragma unroll
  for (int j = 0; j < 4; ++j) {
    const int co = co0 + ty * 4 + j;
    const float bv = bias[co];
    #pragma unroll
    for (int lr = 0; lr < 4; ++lr) {
      float4 o;
      o.x = fmaxf(acc[lr][0][j] + bv, 0.f);
      o.y = fmaxf(acc[lr][1][j] + bv, 0.f);
      o.z = fmaxf(acc[lr][2][j] + bv, 0.f);
      o.w = fmaxf(acc[lr][3][j] + bv, 0.f);
      *(float4*)&h[(size_t)(((b * 512 + co) * 64) + y0 + lr) * 64 + tx * 4] = o;
    }
  }
}

// ---------------- kernel 2: 1x1 heads + softmax + decode + keys ----------------
__global__ __launch_bounds__(256, 1)
void k_heads(const float* __restrict__ h, const float* __restrict__ cls_w,
             const float* __restrict__ cls_b, const float* __restrict__ reg_w,
             const float* __restrict__ reg_b, const int* __restrict__ im_h_p,
             const int* __restrict__ im_w_p, float* __restrict__ out,
             float* __restrict__ ws) {
  __shared__ float w_lds[56 * 512];
  __shared__ float h_lds[64 * 64];
  __shared__ float o_lds[56 * 64];
  const int t = threadIdx.x;
  const int y = blockIdx.x;
  const int b = blockIdx.y;
  for (int i = t; i < 56 * 512; i += 256) {
    const int och = i >> 9, ci = i & 511;
    float v = 0.f;
    if (och < 18) v = cls_w[och * 512 + ci];
    else if (och < 54) v = reg_w[(och - 18) * 512 + ci];
    w_lds[i] = v;
  }
  const int px = t & 63, og = t >> 6;
  float acc[14];
  #pragma unroll
  for (int j = 0; j < 14; ++j) acc[j] = 0.f;
  for (int c0 = 0; c0 < 512; c0 += 64) {
    __syncthreads();
    for (int i = t; i < 4096; i += 256)
      h_lds[i] = h[(size_t)((b * 512 + c0 + (i >> 6)) * 64 + y) * 64 + (i & 63)];
    __syncthreads();
    #pragma unroll 4
    for (int ci = 0; ci < 64; ci += 4) {
      const float hv0 = h_lds[(ci + 0) * 64 + px];
      const float hv1 = h_lds[(ci + 1) * 64 + px];
      const float hv2 = h_lds[(ci + 2) * 64 + px];
      const float hv3 = h_lds[(ci + 3) * 64 + px];
      #pragma unroll
      for (int j = 0; j < 14; ++j) {
        const float4 wv = *(const float4*)&w_lds[(og * 14 + j) * 512 + c0 + ci];
        acc[j] = fmaf(hv0, wv.x, fmaf(hv1, wv.y, fmaf(hv2, wv.z, fmaf(hv3, wv.w, acc[j]))));
      }
    }
  }
  __syncthreads();
  #pragma unroll
  for (int j = 0; j < 14; ++j) {
    const int och = og * 14 + j;
    float bv = 0.f;
    if (och < 18) bv = cls_b[och];
    else if (och < 54) bv = reg_b[och - 18];
    o_lds[och * 64 + px] = acc[j] + bv;
  }
  __syncthreads();
  const float imw1 = (float)(*im_w_p) - 1.0f;
  const float imh1 = (float)(*im_h_p) - 1.0f;
  for (int ii = t; ii < 576; ii += 256) {
    const int p = ii / 9, a = ii - (ii / 9) * 9;
    const int gi = (y * 64 + p) * 9 + a;
    const float l0 = o_lds[(a * 2) * 64 + p];
    const float l1 = o_lds[(a * 2 + 1) * 64 + p];
    out[OFF_CLS + (size_t)b * 73728 + (size_t)gi * 2 + 0] = l0;
    out[OFF_CLS + (size_t)b * 73728 + (size_t)gi * 2 + 1] = l1;
    const float m  = fmaxf(l0, l1);
    const float e0 = expf(l0 - m), e1 = expf(l1 - m);
    const float score = e1 / (e0 + e1);
    float ofs[4];
    #pragma unroll
    for (int d = 0; d < 4; ++d) {
      ofs[d] = o_lds[(18 + a * 4 + d) * 64 + p];
      out[OFF_OFFSETS + (size_t)b * 147456 + (size_t)gi * 4 + d] = ofs[d];
    }
    const float sx = (float)(p * 16), sy = (float)(y * 16);
    const float a0 = c_ab[a][0] + sx, a1 = c_ab[a][1] + sy;
    const float a2 = c_ab[a][2] + sx, a3 = c_ab[a][3] + sy;
    if (b == 0) {
      out[OFF_ANCH + (size_t)gi * 4 + 0] = a0;
      out[OFF_ANCH + (size_t)gi * 4 + 1] = a1;
      out[OFF_ANCH + (size_t)gi * 4 + 2] = a2;
      out[OFF_ANCH + (size_t)gi * 4 + 3] = a3;
    }
    const float aw  = fmaxf(a2 - a0 + 1.0f, 1e-5f);
    const float ah  = fmaxf(a3 - a1 + 1.0f, 1e-5f);
    const float acx = 0.5f * (a0 + a2), acy = 0.5f * (a1 + a3);
    const float tw  = aw * expf(ofs[2]);
    const float th  = ah * expf(ofs[3]);
    const float tcx = acx + ofs[0] * aw;
    const float tcy = acy + ofs[1] * ah;
    float x1 = tcx - 0.5f * (tw - 1.0f);
    float y1 = tcy - 0.5f * (th - 1.0f);
    float x2 = tcx + 0.5f * (tw - 1.0f);
    float y2 = tcy + 0.5f * (th - 1.0f);
    x1 = fminf(fmaxf(x1, 0.f), imw1);
    x2 = fminf(fmaxf(x2, 0.f), imw1);
    y1 = fminf(fmaxf(y1, 0.f), imh1);
    y2 = fminf(fmaxf(y2, 0.f), imh1);
    const bool valid = ((x2 - x1 + 1.0f) >= 16.0f) && ((y2 - y1 + 1.0f) >= 16.0f);
    const unsigned int key = valid ? __float_as_uint(score) : 0u;
    float* bp = ws + BOX_OFF + ((size_t)b * NANCH + gi) * 4;
    bp[0] = x1; bp[1] = y1; bp[2] = x2; bp[3] = y2;
    ((unsigned int*)(ws + KEY_OFF))[(size_t)b * NANCH + gi] = key;
  }
}

// ---------------- kernel 3: exact top-PRE selection (radix threshold + ordered compaction) ----------------
__global__ __launch_bounds__(256, 1)
void k_select(float* __restrict__ ws) {
  const int b = blockIdx.x;
  const int t = threadIdx.x;
  const unsigned int* keys = (const unsigned int*)(ws + KEY_OFF) + (size_t)b * NANCH;
  const float* boxes = ws + BOX_OFF + (size_t)b * NANCH * 4;
  float* sel = ws + SEL_OFF + (size_t)b * 5 * PRE;
  __shared__ unsigned int hist[256];
  __shared__ unsigned int s_prefix, s_need, s_gt_base, s_eq_base;
  __shared__ unsigned int wc_gt[4], wc_eq[4];
  if (t == 0) { s_prefix = 0u; s_need = PRE; s_gt_base = 0u; s_eq_base = 0u; }
  for (int pass = 0; pass < 4; ++pass) {
    hist[t] = 0u;
    __syncthreads();
    const unsigned int prefix = s_prefix;
    const int shift = 24 - 8 * pass;
    for (int i = t; i < NANCH; i += 256) {
      const unsigned int k = keys[i];
      bool match = true;
      if (pass > 0) match = ((k >> (shift + 8)) == (prefix >> (shift + 8)));
      if (match) atomicAdd(&hist[(k >> shift) & 255u], 1u);
    }
    __syncthreads();
    if (t == 0) {
      unsigned int need = s_need, cum = 0u;
      for (int bin = 255; bin >= 0; --bin) {
        const unsigned int hc = hist[bin];
        if (cum + hc >= need) {
          s_prefix = prefix | ((unsigned int)bin << shift);
          s_need = need - cum;
          break;
        }
        cum += hc;
      }
    }
    __syncthreads();
  }
  const unsigned int T = s_prefix;
  const unsigned int need_eq = s_need;
  const unsigned int count_gt = PRE - need_eq;
  const int lane = t & 63, wid = t >> 6;
  const unsigned long long lmask = (1ull << lane) - 1ull;
  for (int i0 = 0; i0 < NANCH; i0 += 256) {
    const int i = i0 + t;
    const unsigned int k = keys[i];
    const bool gt = (k > T);
    const bool eq = (k == T);
    const unsigned long long mg = __ballot(gt);
    const unsigned long long me = __ballot(eq);
    if (lane == 0) { wc_gt[wid] = (unsigned int)__popcll(mg); wc_eq[wid] = (unsigned int)__popcll(me); }
    __syncthreads();
    unsigned int goff = s_gt_base, eoff = s_eq_base, tg = 0u, te = 0u;
    #pragma unroll
    for (int w = 0; w < 4; ++w) {
      if (w < wid) { goff += wc_gt[w]; eoff += wc_eq[w]; }
      tg += wc_gt[w]; te += wc_eq[w];
    }
    int slot = -1;
    if (gt) {
      slot = (int)(goff + (unsigned int)__popcll(mg & lmask));
    } else if (eq) {
      const unsigned int er = eoff + (unsigned int)__popcll(me & lmask);
      if (er < need_eq) slot = (int)(count_gt + er);
    }
    if (slot >= 0) {
      const float* bp = boxes + (size_t)i * 4;
      sel[slot]           = bp[0];
      sel[PRE + slot]     = bp[1];
      sel[2 * PRE + slot] = bp[2];
      sel[3 * PRE + slot] = bp[3];
      sel[4 * PRE + slot] = (k != 0u) ? __uint_as_float(k) : -1.0f;
    }
    __syncthreads();
    if (t == 0) { s_gt_base += tg; s_eq_base += te; }
  }
}

// ---------------- kernel 4: stable LSD radix sort (descending) of the 6000 selected ----------------
// grid 4, block 256. 8 passes x 4-bit digits, all in LDS.
__global__ __launch_bounds__(256, 1)
void k_sort(float* __restrict__ ws) {
  const int b = blockIdx.x, t = threadIdx.x;
  const float* sel = ws + SEL_OFF + (size_t)b * 5 * PRE;
  __shared__ unsigned int kA[PRE], pA[PRE], kB[PRE], pB[PRE];
  __shared__ unsigned int hist[4096];
  __shared__ unsigned int wsum[4];
  for (int i = t; i < PRE; i += 256) {
    const float s = sel[4 * PRE + i];
    kA[i] = (s < 0.f) ? 0u : __float_as_uint(s);
    pA[i] = (unsigned int)i;
  }
  const int i0 = t * 24;                 // threads 0..249 own 24 contiguous items
  const bool own = (t < 250);
  const int lane = t & 63, wid = t >> 6;
  for (int pass = 0; pass < 8; ++pass) {
    unsigned int* kS = (pass & 1) ? kB : kA;
    unsigned int* pS = (pass & 1) ? pB : pA;
    unsigned int* kD = (pass & 1) ? kA : kB;
    unsigned int* pD = (pass & 1) ? pA : pB;
    const int shift = pass * 4;
    __syncthreads();                     // prev scatter (or initial load) done
    #pragma unroll
    for (int j = 0; j < 16; ++j) hist[j * 256 + t] = 0u;
    __syncthreads();
    if (own) {
      for (int j = 0; j < 24; ++j) {
        const unsigned int k = kS[i0 + j];
        const int d = 15 - (int)((k >> shift) & 15u);
        atomicAdd(&hist[d * 256 + t], 1u);
      }
    }
    __syncthreads();
    // block-wide exclusive scan over hist[0..4095] (linear order == (digit, thread))
    unsigned int s = 0;
    #pragma unroll
    for (int j = 0; j < 16; ++j) s += hist[t * 16 + j];
    unsigned int inc = s;
    #pragma unroll
    for (int off = 1; off < 64; off <<= 1) {
      const unsigned int v = __shfl_up(inc, off);
      if (lane >= off) inc += v;
    }
    if (lane == 63) wsum[wid] = inc;
    __syncthreads();
    unsigned int wo = 0;
    #pragma unroll
    for (int w = 0; w < 4; ++w) if (w < wid) wo += wsum[w];
    unsigned int run = wo + inc - s;
    #pragma unroll
    for (int j = 0; j < 16; ++j) {
      const unsigned int v = hist[t * 16 + j];
      hist[t * 16 + j] = run;
      run += v;
    }
    __syncthreads();
    if (own) {
      for (int j = 0; j < 24; ++j) {
        const unsigned int k = kS[i0 + j];
        const unsigned int p = pS[i0 + j];
        const int d = 15 - (int)((k >> shift) & 15u);
        const unsigned int dst = hist[d * 256 + t];
        hist[d * 256 + t] = dst + 1u;    // only thread t touches slot (d,t)
        kD[dst] = k;
        pD[dst] = p;
      }
    }
  }
  __syncthreads();
  unsigned int* skeys = (unsigned int*)(ws + SKEY_OFF) + (size_t)b * PRE;
  float* sx1 = ws + SBOX_OFF + (size_t)(b * 4 + 0) * PRE;
  float* sy1 = ws + SBOX_OFF + (size_t)(b * 4 + 1) * PRE;
  float* sx2 = ws + SBOX_OFF + (size_t)(b * 4 + 2) * PRE;
  float* sy2 = ws + SBOX_OFF + (size_t)(b * 4 + 3) * PRE;
  for (int i = t; i < PRE; i += 256) {
    skeys[i] = kA[i];
    const unsigned int p = pA[i];
    sx1[i] = sel[p];
    sy1[i] = sel[PRE + p];
    sx2[i] = sel[2 * PRE + p];
    sy2[i] = sel[3 * PRE + p];
  }
}

// ---------------- kernel 5: all-pairs IoU suppression bitmask ----------------
// grid (94 colwords, 24 rowblocks, 4 batches), block 256. mask[b][row][cw] bit i set
// iff picking sorted-box `row` suppresses sorted-box `cw*64+i` (incl. diagonal).
__global__ __launch_bounds__(256)
void k_mask(const float* __restrict__ ws, unsigned long long* __restrict__ mask) {
  const int cw = blockIdx.x, rb = blockIdx.y, b = blockIdx.z;
  const int t = threadIdx.x;
  __shared__ float cx1[64], cy1[64], cx2[64], cy2[64], car[64];
  __shared__ int cval[64];
  const float* bx1 = ws + SBOX_OFF + (size_t)(b * 4 + 0) * PRE;
  const float* by1 = ws + SBOX_OFF + (size_t)(b * 4 + 1) * PRE;
  const float* bx2 = ws + SBOX_OFF + (size_t)(b * 4 + 2) * PRE;
  const float* by2 = ws + SBOX_OFF + (size_t)(b * 4 + 3) * PRE;
  if (t < 64) {
    const int c = cw * 64 + t;
    if (c < PRE) {
      const float x1 = bx1[c], y1 = by1[c], x2 = bx2[c], y2 = by2[c];
      cx1[t] = x1; cy1[t] = y1; cx2[t] = x2; cy2[t] = y2;
      car[t] = (x2 - x1) * (y2 - y1);
      cval[t] = 1;
    } else cval[t] = 0;
  }
  __syncthreads();
  const int row = rb * 256 + t;
  if (row >= PRE) return;
  const float rx1 = bx1[row], ry1 = by1[row], rx2 = bx2[row], ry2 = by2[row];
  const float rar = (rx2 - rx1) * (ry2 - ry1);
  unsigned long long word = 0ull;
  for (int i = 0; i < 64; ++i) {
    if (!cval[i]) continue;
    const float xx1 = fmaxf(rx1, cx1[i]);
    const float yy1 = fmaxf(ry1, cy1[i]);
    const float xx2 = fminf(rx2, cx2[i]);
    const float yy2 = fminf(ry2, cy2[i]);
    const float inter = fmaxf(xx2 - xx1, 0.f) * fmaxf(yy2 - yy1, 0.f);
    const float iou = inter / (((rar + car[i]) - inter) + 1e-12f);
    const int c = cw * 64 + i;
    if (iou > 0.7f || c == row) word |= (1ull << i);
  }
  mask[((size_t)b * PRE + row) * 94 + cw] = word;
}

// ---------------- kernel 6: serial NMS scan, one wave per batch, zero barriers ----------------
__global__ __launch_bounds__(64, 1)
void k_nms2(const float* __restrict__ ws, const unsigned long long* __restrict__ maskg,
            float* __restrict__ out) {
  const int b = blockIdx.x, l = threadIdx.x;
  const unsigned int* skeys = (const unsigned int*)(ws + SKEY_OFF) + (size_t)b * PRE;
  const float* bx1 = ws + SBOX_OFF + (size_t)(b * 4 + 0) * PRE;
  const float* by1 = ws + SBOX_OFF + (size_t)(b * 4 + 1) * PRE;
  const float* bx2 = ws + SBOX_OFF + (size_t)(b * 4 + 2) * PRE;
  const float* by2 = ws + SBOX_OFF + (size_t)(b * 4 + 3) * PRE;
  const unsigned long long* mask = maskg + (size_t)b * PRE * 94;
  // alive bitset: lane l owns word l (a0) and word 64+l for l<30 (a1). 94*64 >= 6000.
  unsigned long long a0 = ~0ull;
  unsigned long long a1 = (l < 29) ? ~0ull : (l == 29 ? ((1ull << 48) - 1ull) : 0ull);
  float fx1 = 0.f, fy1 = 0.f, fx2 = 0.f, fy2 = 0.f;
  for (int it = 0; it < POST; ++it) {
    const unsigned long long bm0 = __ballot(a0 != 0ull);
    const unsigned long long bm1 = __ballot(a1 != 0ull);
    int pos = -1;
    if (bm0 | bm1) {
      int word;
      unsigned long long bits;
      if (bm0) {
        const int wsel = (int)__builtin_ctzll(bm0);
        word = wsel;
        bits = __shfl(a0, wsel);
      } else {
        const int wsel = (int)__builtin_ctzll(bm1);
        word = 64 + wsel;
        bits = __shfl(a1, wsel);
      }
      pos = word * 64 + (int)__builtin_ctzll(bits);
    }
    float ox1 = fx1, oy1 = fy1, ox2 = fx2, oy2 = fy2;
    if (pos >= 0) {
      const unsigned int k = skeys[pos];
      const float x1 = bx1[pos], y1 = by1[pos], x2 = bx2[pos], y2 = by2[pos];
      if (it == 0) { fx1 = x1; fy1 = y1; fx2 = x2; fy2 = y2; }
      if (k != 0u) { ox1 = x1; oy1 = y1; ox2 = x2; oy2 = y2; }
      else         { ox1 = fx1; oy1 = fy1; ox2 = fx2; oy2 = fy2; }
      const unsigned long long* mrow = mask + (size_t)pos * 94;
      a0 &= ~mrow[l];
      if (l < 30) a1 &= ~mrow[64 + l];
    }
    if (l == 0) {
      const size_t o = OFF_ROIS + ((size_t)b * POST + it) * 4;
      out[o + 0] = ox1;
      out[o + 1] = oy1;
      out[o + 2] = ox2;
      out[o + 3] = oy2;
    }
  }
  for (int i = l; i < POST; i += 64)
    out[OFF_RIDX + (size_t)b * POST + i] = (float)b;
}

extern "C" void kernel_launch(void* const* d_in, const int* in_sizes, int n_in,
                              void* d_out, int out_size, void* d_ws, size_t ws_size,
                              hipStream_t stream) {
  const float* x      = (const float*)d_in[0];
  const float* conv_w = (const float*)d_in[1];
  const float* conv_b = (const float*)d_in[2];
  const float* cls_w  = (const float*)d_in[3];
  const float* cls_b  = (const float*)d_in[4];
  const float* reg_w  = (const float*)d_in[5];
  const float* reg_b  = (const float*)d_in[6];
  const int*   im_h   = (const int*)d_in[7];
  const int*   im_w   = (const int*)d_in[8];
  float* out = (float*)d_out;
  float* ws  = (float*)d_ws;
  unsigned long long* mask = (unsigned long long*)(ws + H_OFF);  // aliases conv output (dead after k_heads)

  k_transpose_w<<<(512 * 512 * 9 + 255) / 256, 256, 0, stream>>>(conv_w, ws + WT_OFF);
  k_conv3<<<dim3(16, 8, 4), 256, 0, stream>>>(x, ws + WT_OFF, conv_b, ws + H_OFF);
  k_heads<<<dim3(64, 4), 256, 0, stream>>>(ws + H_OFF, cls_w, cls_b, reg_w, reg_b,
                                           im_h, im_w, out, ws);
  k_select<<<4, 256, 0, stream>>>(ws);
  k_sort<<<4, 256, 0, stream>>>(ws);
  k_mask<<<dim3(94, 24, 4), 256, 0, stream>>>(ws, mask);
  k_nms2<<<4, 64, 0, stream>>>(ws, mask, out);
}